// Round 11
// baseline (226.129 us; speedup 1.0000x reference)
//
#include <hip/hip_runtime.h>

#define NN 50000
#define NE 800000
#define NF 64
#define NG 64
#define NC 16
#define NSLICE 16
#define NBKT 196   // buckets of 256 nodes: ceil(NN/256)
#define CH 4096    // edges per scatter block
#define SCAP 6144  // per-bucket LDS stage capacity (mean 4096, sigma~64)

// ---- CSR build: two-level bucket counting sort ---------------------------

__global__ void zero_kernel(int* __restrict__ p, int n) {
    for (int i = threadIdx.x; i < n; i += 256) p[i] = 0;
}

// P1a: per-bucket histogram (LDS-staged)
__global__ void bhist_kernel(const int* __restrict__ dst, int* __restrict__ bhist, int E) {
    __shared__ int lh[NBKT];
    for (int i = threadIdx.x; i < NBKT; i += 256) lh[i] = 0;
    __syncthreads();
    int e = (blockIdx.x * 256 + threadIdx.x) * 4;
    if (e + 3 < E) {
        int4 d = *(const int4*)&dst[e];
        atomicAdd(&lh[d.x >> 8], 1); atomicAdd(&lh[d.y >> 8], 1);
        atomicAdd(&lh[d.z >> 8], 1); atomicAdd(&lh[d.w >> 8], 1);
    } else {
        for (int k = e; k < E; ++k) atomicAdd(&lh[dst[k] >> 8], 1);
    }
    __syncthreads();
    for (int i = threadIdx.x; i < NBKT; i += 256) if (lh[i]) atomicAdd(&bhist[i], lh[i]);
}

// P1b: scan bucket hist -> bucket_base (+total), init bucket cursors
__global__ void bscan_kernel(const int* __restrict__ bhist, int* __restrict__ bbase,
                             int* __restrict__ bcur) {
    int tid = threadIdx.x, lane = tid & 63, wid = tid >> 6;
    int v = (tid < NBKT) ? bhist[tid] : 0;
    int s = v;
    #pragma unroll
    for (int d = 1; d < 64; d <<= 1) { int t = __shfl_up(s, d, 64); if (lane >= d) s += t; }
    __shared__ int ws[4];
    if (lane == 63) ws[wid] = s;
    __syncthreads();
    int woff = 0;
    for (int k = 0; k < wid; ++k) woff += ws[k];
    int excl = woff + s - v;
    if (tid < NBKT) { bbase[tid] = excl; bcur[tid] = excl; }
    if (tid == NBKT) bbase[NBKT] = excl;
}

// P1c: scatter edges into bucket regions of `pairs`, LDS-staged so global
// writes are contiguous bursts per bucket.
__global__ void __launch_bounds__(256) bscatter_kernel(
        const int* __restrict__ src, const int* __restrict__ dst,
        int* __restrict__ bcur, int2* __restrict__ pairs, int E) {
    __shared__ int lhist[NBKT];
    __shared__ int lbase[NBKT];
    __shared__ int gbase[NBKT];
    __shared__ int2 stage[CH];
    __shared__ short bktOf[CH];
    __shared__ int ws[4];
    int tid = threadIdx.x, lane = tid & 63, wid = tid >> 6;
    for (int i = tid; i < NBKT; i += 256) lhist[i] = 0;
    __syncthreads();
    int e0 = blockIdx.x * CH;
    int m = E - e0; if (m > CH) m = CH;
    int es[16], ed[16], er[16];
    #pragma unroll
    for (int k = 0; k < 16; ++k) {
        int i = tid + k * 256;
        if (i < m) {
            es[k] = src[e0 + i];
            ed[k] = dst[e0 + i];
            er[k] = atomicAdd(&lhist[ed[k] >> 8], 1);
        }
    }
    __syncthreads();
    {
        int v = (tid < NBKT) ? lhist[tid] : 0;
        int s = v;
        #pragma unroll
        for (int d = 1; d < 64; d <<= 1) { int t = __shfl_up(s, d, 64); if (lane >= d) s += t; }
        if (lane == 63) ws[wid] = s;
        __syncthreads();
        int woff = 0;
        for (int k = 0; k < wid; ++k) woff += ws[k];
        if (tid < NBKT) {
            lbase[tid] = woff + s - v;
            gbase[tid] = v ? atomicAdd(&bcur[tid], v) : 0;
        }
    }
    __syncthreads();
    #pragma unroll
    for (int k = 0; k < 16; ++k) {
        int i = tid + k * 256;
        if (i < m) {
            int b = ed[k] >> 8;
            int pos = lbase[b] + er[k];
            stage[pos] = make_int2(es[k], ed[k]);
            bktOf[pos] = (short)b;
        }
    }
    __syncthreads();
    for (int i = tid; i < m; i += 256) {
        int b = bktOf[i];
        pairs[gbase[b] + (i - lbase[b])] = stage[i];
    }
}

// P2: per-bucket counting sort by dst -> csr_src (coalesced, PRE-SHIFTED by
// <<4 = float4-row offset), row_ptr, dinv, fused prescale Xs = x*dinv.
__global__ void __launch_bounds__(256) bsort_kernel(
        const int2* __restrict__ pairs, const int* __restrict__ bbase,
        int* __restrict__ csr_src, int* __restrict__ row_ptr, float* __restrict__ dinv,
        const float* __restrict__ x, float* __restrict__ Xs, int n) {
    __shared__ int lh[256];
    __shared__ int lcur[256];
    __shared__ float sdv[256];
    __shared__ int ws[4];
    __shared__ int ssrc[SCAP];
    int tid = threadIdx.x, lane = tid & 63, wid = tid >> 6;
    int b = blockIdx.x;
    int n0 = b << 8;
    int nodes = n - n0; if (nodes > 256) nodes = 256;
    int g0 = bbase[b], cnt = bbase[b + 1] - g0;
    lh[tid] = 0;
    __syncthreads();
    for (int i = tid; i < cnt; i += 256) atomicAdd(&lh[pairs[g0 + i].y - n0], 1);
    __syncthreads();
    int v = lh[tid];
    int s = v;
    #pragma unroll
    for (int d = 1; d < 64; d <<= 1) { int t = __shfl_up(s, d, 64); if (lane >= d) s += t; }
    if (lane == 63) ws[wid] = s;
    __syncthreads();
    int woff = 0;
    for (int k = 0; k < wid; ++k) woff += ws[k];
    int excl = woff + s - v;
    lcur[tid] = excl;
    float dv = rsqrtf((float)v + 1.0f);
    sdv[tid] = dv;
    if (tid < nodes) {
        row_ptr[n0 + tid] = g0 + excl;
        dinv[n0 + tid] = dv;
    }
    if (b == NBKT - 1 && tid == 0) row_ptr[n] = bbase[NBKT];
    __syncthreads();
    if (cnt <= SCAP) {
        for (int i = tid; i < cnt; i += 256) {
            int2 p = pairs[g0 + i];
            int pos = atomicAdd(&lcur[p.y - n0], 1);
            ssrc[pos] = p.x << 4;
        }
        __syncthreads();
        for (int i = tid; i < cnt; i += 256) csr_src[g0 + i] = ssrc[i];
    } else {
        for (int i = tid; i < cnt; i += 256) {
            int2 p = pairs[g0 + i];
            int pos = atomicAdd(&lcur[p.y - n0], 1);
            csr_src[g0 + pos] = p.x << 4;
        }
    }
    const float4* x4 = (const float4*)x;
    float4* Xs4 = (float4*)Xs;
    int t0 = n0 << 4;
    int tcnt = nodes << 4;
    for (int t = tid; t < tcnt; t += 256) {
        float4 vv = x4[t0 + t];
        float d = sdv[t >> 4];
        vv.x *= d; vv.y *= d; vv.z *= d; vv.w *= d;
        Xs4[t0 + t] = vv;
    }
}

// ---- fused GCN layer: one node per 16-lane group --------------------------
// Wave = 4 groups = 4 nodes gathered CONCURRENTLY (16 independent row loads
// in flight per wave). Group's 16 lanes hold the node's full agg (float4 each)
// -> no cross-group shuffles. Matvec: agg staged in per-wave LDS row (same
// wave produces+consumes -> NO __syncthreads in the flow), group-broadcast
// a-reads + row-broadcast W-reads, all conflict-free.
__global__ void __launch_bounds__(256) layer_kernel(
        const float* __restrict__ Xs, const int* __restrict__ row_ptr,
        const int* __restrict__ csr_src, const float* __restrict__ dinv,
        const float* __restrict__ W, const float* __restrict__ bias,
        float* __restrict__ out, int n, int do_relu, int scale_out) {
    __shared__ __align__(16) float sW[64 * 65 + 4];    // row k at k*65
    __shared__ __align__(16) float sAgg[16 * 65 + 4];  // node slot q at q*65
    for (int i = threadIdx.x; i < 4096; i += 256) {
        int k = i >> 6, j = i & 63;
        sW[k * 65 + j] = W[i];
    }
    __syncthreads();

    int tid = threadIdx.x;
    int wv = tid >> 6, lane = tid & 63;
    int g = lane >> 4, sub = lane & 15;
    int q = wv * 4 + g;                  // node slot in block (0..15)
    int node = blockIdx.x * 16 + q;      // grid = NN/16 exactly
    const float4* X4 = (const float4*)Xs;

    int s0 = row_ptr[node], s1 = row_ptr[node + 1];
    int deg = s1 - s0;
    float4 bias4 = ((const float4*)bias)[sub];

    // self-loop row (already dinv-scaled) initializes chain 0
    float4 acc0 = X4[(unsigned)(node * 16 + sub)];
    float4 acc1 = make_float4(0.f, 0.f, 0.f, 0.f);
    float4 acc2 = make_float4(0.f, 0.f, 0.f, 0.f);
    float4 acc3 = make_float4(0.f, 0.f, 0.f, 0.f);

    for (int t0 = 0; t0 < deg; t0 += 16) {
        int m = deg - t0; if (m > 16) m = 16;
        // group's 16-edge index tile (clamped within this node's range)
        int idx = csr_src[s0 + t0 + ((sub < m) ? sub : (m - 1))];
        #pragma unroll
        for (int e = 0; e < 16; e += 4) {
            int c0 = (e + 0 < m) ? (e + 0) : 0;
            int c1 = (e + 1 < m) ? (e + 1) : 0;
            int c2 = (e + 2 < m) ? (e + 2) : 0;
            int c3 = (e + 3 < m) ? (e + 3) : 0;
            int i0 = __shfl(idx, c0, 16);
            int i1 = __shfl(idx, c1, 16);
            int i2 = __shfl(idx, c2, 16);
            int i3 = __shfl(idx, c3, 16);
            float w0 = (e + 0 < m) ? 1.f : 0.f;
            float w1 = (e + 1 < m) ? 1.f : 0.f;
            float w2 = (e + 2 < m) ? 1.f : 0.f;
            float w3 = (e + 3 < m) ? 1.f : 0.f;
            float4 v0 = X4[(unsigned)(i0 + sub)];
            float4 v1 = X4[(unsigned)(i1 + sub)];
            float4 v2 = X4[(unsigned)(i2 + sub)];
            float4 v3 = X4[(unsigned)(i3 + sub)];
            acc0.x = fmaf(w0, v0.x, acc0.x); acc0.y = fmaf(w0, v0.y, acc0.y);
            acc0.z = fmaf(w0, v0.z, acc0.z); acc0.w = fmaf(w0, v0.w, acc0.w);
            acc1.x = fmaf(w1, v1.x, acc1.x); acc1.y = fmaf(w1, v1.y, acc1.y);
            acc1.z = fmaf(w1, v1.z, acc1.z); acc1.w = fmaf(w1, v1.w, acc1.w);
            acc2.x = fmaf(w2, v2.x, acc2.x); acc2.y = fmaf(w2, v2.y, acc2.y);
            acc2.z = fmaf(w2, v2.z, acc2.z); acc2.w = fmaf(w2, v2.w, acc2.w);
            acc3.x = fmaf(w3, v3.x, acc3.x); acc3.y = fmaf(w3, v3.y, acc3.y);
            acc3.z = fmaf(w3, v3.z, acc3.z); acc3.w = fmaf(w3, v3.w, acc3.w);
        }
    }
    float4 acc;
    acc.x = (acc0.x + acc1.x) + (acc2.x + acc3.x);
    acc.y = (acc0.y + acc1.y) + (acc2.y + acc3.y);
    acc.z = (acc0.z + acc1.z) + (acc2.z + acc3.z);
    acc.w = (acc0.w + acc1.w) + (acc2.w + acc3.w);

    // stage agg in this wave's LDS row (same-wave producer/consumer)
    *(float4*)&sAgg[q * 65 + 4 * sub] = acc;

    // matvec: lane computes out cols 4sub..4sub+3 of its group's node
    float4 o = make_float4(0.f, 0.f, 0.f, 0.f);
    #pragma unroll
    for (int c = 0; c < 16; ++c) {
        float4 a  = *(const float4*)&sAgg[q * 65 + 4 * c];          // group bcast
        float4 r0 = *(const float4*)&sW[(4 * c + 0) * 65 + 4 * sub];
        float4 r1 = *(const float4*)&sW[(4 * c + 1) * 65 + 4 * sub];
        float4 r2 = *(const float4*)&sW[(4 * c + 2) * 65 + 4 * sub];
        float4 r3 = *(const float4*)&sW[(4 * c + 3) * 65 + 4 * sub];
        o.x = fmaf(a.x, r0.x, o.x); o.y = fmaf(a.x, r0.y, o.y);
        o.z = fmaf(a.x, r0.z, o.z); o.w = fmaf(a.x, r0.w, o.w);
        o.x = fmaf(a.y, r1.x, o.x); o.y = fmaf(a.y, r1.y, o.y);
        o.z = fmaf(a.y, r1.z, o.z); o.w = fmaf(a.y, r1.w, o.w);
        o.x = fmaf(a.z, r2.x, o.x); o.y = fmaf(a.z, r2.y, o.y);
        o.z = fmaf(a.z, r2.z, o.z); o.w = fmaf(a.z, r2.w, o.w);
        o.x = fmaf(a.w, r3.x, o.x); o.y = fmaf(a.w, r3.y, o.y);
        o.z = fmaf(a.w, r3.z, o.z); o.w = fmaf(a.w, r3.w, o.w);
    }
    float di = dinv[node];
    o.x = fmaf(o.x, di, bias4.x); o.y = fmaf(o.y, di, bias4.y);
    o.z = fmaf(o.z, di, bias4.z); o.w = fmaf(o.w, di, bias4.w);
    if (do_relu) {
        o.x = fmaxf(o.x, 0.f); o.y = fmaxf(o.y, 0.f);
        o.z = fmaxf(o.z, 0.f); o.w = fmaxf(o.w, 0.f);
    }
    if (scale_out) { o.x *= di; o.y *= di; o.z *= di; o.w *= di; }
    *(float4*)&out[(unsigned)(node * 64 + 4 * sub)] = o;
}

// ---- pooling / classifier ------------------------------------------------

__global__ void pool1_kernel(const float* __restrict__ H, const int* __restrict__ batch,
                             float* __restrict__ partial, int n) {
    int g = blockIdx.x >> 4, sl = blockIdx.x & (NSLICE - 1);
    int lo = 0, hi = n;
    while (lo < hi) { int m = (lo + hi) >> 1; if (batch[m] < g) lo = m + 1; else hi = m; }
    int start = lo;
    lo = start; hi = n;
    while (lo < hi) { int m = (lo + hi) >> 1; if (batch[m] < g + 1) lo = m + 1; else hi = m; }
    int end = lo;
    int len = end - start;
    int ss = start + (int)((long long)len * sl / NSLICE);
    int se = start + (int)((long long)len * (sl + 1) / NSLICE);

    int f = threadIdx.x & 63, c = threadIdx.x >> 6;
    float s = 0.f, m = -INFINITY;
    for (int i = ss + c; i < se; i += 4) {
        float v = H[i * NF + f];
        s += v; m = fmaxf(m, v);
    }
    __shared__ float ssh[4][64], smh[4][64];
    ssh[c][f] = s; smh[c][f] = m;
    __syncthreads();
    if (c == 0) {
        float sum = ssh[0][f] + ssh[1][f] + ssh[2][f] + ssh[3][f];
        float mx = fmaxf(fmaxf(smh[0][f], smh[1][f]), fmaxf(smh[2][f], smh[3][f]));
        partial[(size_t)blockIdx.x * 128 + f] = sum;
        partial[(size_t)blockIdx.x * 128 + 64 + f] = mx;
    }
}

__global__ void pool2_kernel(const float* __restrict__ partial, const int* __restrict__ batch,
                             const float* __restrict__ Wlin, const float* __restrict__ blin,
                             float* __restrict__ out, int n) {
    int g = blockIdx.x;
    int t = threadIdx.x;  // 128
    __shared__ float pooled[128];
    if (t < 64) {
        float sum = 0.f;
        for (int sl = 0; sl < NSLICE; ++sl) sum += partial[((size_t)g * NSLICE + sl) * 128 + t];
        int lo = 0, hi = n;
        while (lo < hi) { int m = (lo + hi) >> 1; if (batch[m] < g) lo = m + 1; else hi = m; }
        int start = lo;
        lo = start; hi = n;
        while (lo < hi) { int m = (lo + hi) >> 1; if (batch[m] < g + 1) lo = m + 1; else hi = m; }
        int cnt = lo - start;
        pooled[t] = sum / fmaxf((float)cnt, 1.0f);
    } else {
        int f = t - 64;
        float mx = -INFINITY;
        for (int sl = 0; sl < NSLICE; ++sl)
            mx = fmaxf(mx, partial[((size_t)g * NSLICE + sl) * 128 + 64 + f]);
        pooled[t] = mx;
    }
    __syncthreads();
    if (t < NC) {
        float acc = blin[t];
        #pragma unroll 8
        for (int k = 0; k < 128; ++k) acc = fmaf(pooled[k], Wlin[k * NC + t], acc);
        out[g * NC + t] = acc;
    }
}

// ---- launch ---------------------------------------------------------------

extern "C" void kernel_launch(void* const* d_in, const int* in_sizes, int n_in,
                              void* d_out, int out_size, void* d_ws, size_t ws_size,
                              hipStream_t stream) {
    const float* x     = (const float*)d_in[0];
    const int*   ei    = (const int*)d_in[1];
    const int*   batch = (const int*)d_in[2];
    const float* W1    = (const float*)d_in[3];
    const float* b1    = (const float*)d_in[4];
    const float* W2    = (const float*)d_in[5];
    const float* b2    = (const float*)d_in[6];
    const float* W3    = (const float*)d_in[7];
    const float* b3    = (const float*)d_in[8];
    const float* Wlin  = (const float*)d_in[9];
    const float* blin  = (const float*)d_in[10];
    const int* src = ei;
    const int* dst = ei + NE;
    float* out = (float*)d_out;

    // workspace layout (all offsets keep 16B alignment)
    int*   bhist   = (int*)d_ws;                    // 256
    int*   bbase   = bhist + 256;                   // 256 (uses NBKT+1)
    int*   bcur    = bbase + 256;                   // 256
    int*   row_ptr = bcur + 256;                    // 50008
    int*   csr_src = row_ptr + 50008;               // 800000
    float* dinv    = (float*)(csr_src + NE);        // 50008
    float* bufA    = dinv + 50008;                  // 3.2M
    float* bufB    = bufA + (size_t)NN * NF;        // 3.2M (aliased as pairs in build)
    float* partial = bufB + (size_t)NN * NF;        // 131072
    int2*  pairs   = (int2*)bufB;                   // 6.4MB <= bufB, used only pre-layer

    // CSR build (bucket counting sort) + dinv + prescale
    zero_kernel<<<1, 256, 0, stream>>>(bhist, 256);
    bhist_kernel<<<(NE / 4 + 255) / 256, 256, 0, stream>>>(dst, bhist, NE);
    bscan_kernel<<<1, 256, 0, stream>>>(bhist, bbase, bcur);
    bscatter_kernel<<<(NE + CH - 1) / CH, 256, 0, stream>>>(src, dst, bcur, pairs, NE);
    bsort_kernel<<<NBKT, 256, 0, stream>>>(pairs, bbase, csr_src, row_ptr, dinv, x, bufA, NN);

    // 3 fused GCN layers (16 nodes per block, 1 node per 16-lane group)
    int lgrid = NN / 16;  // 3125
    layer_kernel<<<lgrid, 256, 0, stream>>>(bufA, row_ptr, csr_src, dinv, W1, b1,
                                            bufB, NN, 1, 1);
    layer_kernel<<<lgrid, 256, 0, stream>>>(bufB, row_ptr, csr_src, dinv, W2, b2,
                                            bufA, NN, 1, 1);
    layer_kernel<<<lgrid, 256, 0, stream>>>(bufA, row_ptr, csr_src, dinv, W3, b3,
                                            bufB, NN, 0, 0);

    // two-stage pool + fused classifier
    pool1_kernel<<<NG * NSLICE, 256, 0, stream>>>(bufB, batch, partial, NN);
    pool2_kernel<<<NG, 128, 0, stream>>>(partial, batch, Wlin, blin, out, NN);
}

// Round 12
// 156.835 us; speedup vs baseline: 1.4418x; 1.4418x over previous
//
#include <hip/hip_runtime.h>

#define NN 50000
#define NE 800000
#define NF 64
#define NG 64
#define NC 16
#define NSLICE 16
#define NBKT 196   // buckets of 256 nodes
#define CH 4096    // edges per scatter block
#define CAPB 4608  // fixed per-bucket capacity (mean 4096 + 8 sigma)

// ---- CSR build: fixed-capacity bucket sort (no global hist/scan) ----------

__global__ void init_kernel(int* __restrict__ bcur) {
    int t = threadIdx.x;
    if (t < NBKT) bcur[t] = t * CAPB;
}

// scatter edges into fixed bucket regions of `pairs`; LDS-staged so global
// writes are contiguous bursts per bucket. Space reserved via atomic bcur.
__global__ void __launch_bounds__(256) bscatter_kernel(
        const int* __restrict__ src, const int* __restrict__ dst,
        int* __restrict__ bcur, int2* __restrict__ pairs, int E) {
    __shared__ int lhist[NBKT];
    __shared__ int lbase[NBKT];
    __shared__ int gbase[NBKT];
    __shared__ int2 stage[CH];
    __shared__ short bktOf[CH];
    __shared__ int ws[4];
    int tid = threadIdx.x, lane = tid & 63, wid = tid >> 6;
    for (int i = tid; i < NBKT; i += 256) lhist[i] = 0;
    __syncthreads();
    int e0 = blockIdx.x * CH;
    int m = E - e0; if (m > CH) m = CH;
    int es[16], ed[16], er[16];
    #pragma unroll
    for (int k = 0; k < 16; ++k) {
        int i = tid + k * 256;
        if (i < m) {
            es[k] = src[e0 + i];
            ed[k] = dst[e0 + i];
            er[k] = atomicAdd(&lhist[ed[k] >> 8], 1);
        }
    }
    __syncthreads();
    {   // block scan of lhist + reserve global space per bucket
        int v = (tid < NBKT) ? lhist[tid] : 0;
        int s = v;
        #pragma unroll
        for (int d = 1; d < 64; d <<= 1) { int t = __shfl_up(s, d, 64); if (lane >= d) s += t; }
        if (lane == 63) ws[wid] = s;
        __syncthreads();
        int woff = 0;
        for (int k = 0; k < wid; ++k) woff += ws[k];
        if (tid < NBKT) {
            lbase[tid] = woff + s - v;
            gbase[tid] = v ? atomicAdd(&bcur[tid], v) : 0;
        }
    }
    __syncthreads();
    #pragma unroll
    for (int k = 0; k < 16; ++k) {
        int i = tid + k * 256;
        if (i < m) {
            int b = ed[k] >> 8;
            int pos = lbase[b] + er[k];
            stage[pos] = make_int2(es[k], ed[k]);
            bktOf[pos] = (short)b;
        }
    }
    __syncthreads();
    for (int i = tid; i < m; i += 256) {
        int b = bktOf[i];
        int pos = gbase[b] + (i - lbase[b]);
        if (pos < (b + 1) * CAPB)   // overflow guard (unreachable at 8 sigma)
            pairs[pos] = stage[i];
    }
}

// per-bucket counting sort by dst -> csr_src (coalesced, PRE-SHIFTED by <<4),
// rse = (start,end) per node, dinv, fused prescale Xs = x*dinv.
__global__ void __launch_bounds__(256) bsort_kernel(
        const int2* __restrict__ pairs, const int* __restrict__ bcur,
        int* __restrict__ csr_src, int2* __restrict__ rse, float* __restrict__ dinv,
        const float* __restrict__ x, float* __restrict__ Xs, int n) {
    __shared__ int lh[256];
    __shared__ int lcur[256];
    __shared__ float sdv[256];
    __shared__ int ws[4];
    __shared__ int ssrc[CAPB];
    int tid = threadIdx.x, lane = tid & 63, wid = tid >> 6;
    int b = blockIdx.x;
    int n0 = b << 8;
    int nodes = n - n0; if (nodes > 256) nodes = 256;
    int g0 = b * CAPB;
    int cnt = bcur[b] - g0; if (cnt > CAPB) cnt = CAPB;
    lh[tid] = 0;
    __syncthreads();
    for (int i = tid; i < cnt; i += 256) atomicAdd(&lh[pairs[g0 + i].y - n0], 1);
    __syncthreads();
    int v = lh[tid];
    int s = v;
    #pragma unroll
    for (int d = 1; d < 64; d <<= 1) { int t = __shfl_up(s, d, 64); if (lane >= d) s += t; }
    if (lane == 63) ws[wid] = s;
    __syncthreads();
    int woff = 0;
    for (int k = 0; k < wid; ++k) woff += ws[k];
    int excl = woff + s - v;
    lcur[tid] = excl;
    float dv = rsqrtf((float)v + 1.0f);
    sdv[tid] = dv;
    if (tid < nodes) {
        rse[n0 + tid] = make_int2(g0 + excl, g0 + excl + v);
        dinv[n0 + tid] = dv;
    }
    __syncthreads();
    for (int i = tid; i < cnt; i += 256) {
        int2 p = pairs[g0 + i];
        int pos = atomicAdd(&lcur[p.y - n0], 1);
        ssrc[pos] = p.x << 4;
    }
    __syncthreads();
    for (int i = tid; i < cnt; i += 256) csr_src[g0 + i] = ssrc[i];
    // fused prescale for this node range
    const float4* x4 = (const float4*)x;
    float4* Xs4 = (float4*)Xs;
    int t0 = n0 << 4;
    int tcnt = nodes << 4;
    for (int t = tid; t < tcnt; t += 256) {
        float4 vv = x4[t0 + t];
        float d = sdv[t >> 4];
        vv.x *= d; vv.y *= d; vv.z *= d; vv.w *= d;
        Xs4[t0 + t] = vv;
    }
}

// ---- fused GCN layer (R8 structure; 8 waves/block share W staging) --------
// Per node: wave gathers neighbor rows (4 grp x 16 lanes x float4),
// xor-reduces, then matvec via readlane broadcast against xor-swizzled W^T
// in LDS (reads 2-way = free; staging writes permutation-per-phase = free).
__global__ void __launch_bounds__(512) layer_kernel(
        const float* __restrict__ Xs, const int2* __restrict__ rse,
        const int* __restrict__ csr_src, const float* __restrict__ dinv,
        const float* __restrict__ W, const float* __restrict__ bias,
        float* __restrict__ out, int n, int do_relu, int scale_out) {
    __shared__ __align__(16) float sWt[64 * 64];  // row j: 16 xor-swizzled chunks
    {
        int j = threadIdx.x & 63;
        int c0 = (threadIdx.x >> 6) * 2;
        #pragma unroll
        for (int it = 0; it < 2; ++it) {
            int c = c0 + it;
            float4 w;
            w.x = W[(4 * c + 0) * 64 + j];   // coalesced 256B per phase
            w.y = W[(4 * c + 1) * 64 + j];
            w.z = W[(4 * c + 2) * 64 + j];
            w.w = W[(4 * c + 3) * 64 + j];
            *(float4*)&sWt[j * 64 + ((c ^ (j & 15)) * 4)] = w;  // conflict-free
        }
    }
    __syncthreads();

    int wv = threadIdx.x >> 6, lane = threadIdx.x & 63;
    int grp = lane >> 4, sub = lane & 15;
    const float4* X4 = (const float4*)Xs;
    int base = blockIdx.x * 32 + wv * 4;
    float bj = bias[lane];

    for (int nd = 0; nd < 4; ++nd) {
        int node = base + nd;
        if (node >= n) break;   // wave-uniform

        float4 acc = make_float4(0.f, 0.f, 0.f, 0.f);
        int2 se = rse[node];
        int s0 = se.x, s1 = se.y;
        for (int tb = s0; tb < s1; tb += 64) {
            int m = s1 - tb; if (m > 64) m = 64;
            int ld = (lane < m) ? lane : (m - 1);
            int idx = csr_src[tb + ld];
            for (int e0 = grp; e0 < m; e0 += 16) {
                int e1 = e0 + 4, e2 = e0 + 8, e3 = e0 + 12;
                int i0 = __shfl(idx, e0, 64);
                int i1 = __shfl(idx, (e1 < m) ? e1 : e0, 64);
                int i2 = __shfl(idx, (e2 < m) ? e2 : e0, 64);
                int i3 = __shfl(idx, (e3 < m) ? e3 : e0, 64);
                float w1 = (e1 < m) ? 1.f : 0.f;
                float w2 = (e2 < m) ? 1.f : 0.f;
                float w3 = (e3 < m) ? 1.f : 0.f;
                float4 v0 = X4[(unsigned)(i0 + sub)];
                float4 v1 = X4[(unsigned)(i1 + sub)];
                float4 v2 = X4[(unsigned)(i2 + sub)];
                float4 v3 = X4[(unsigned)(i3 + sub)];
                acc.x += v0.x; acc.y += v0.y; acc.z += v0.z; acc.w += v0.w;
                acc.x = fmaf(w1, v1.x, acc.x); acc.y = fmaf(w1, v1.y, acc.y);
                acc.z = fmaf(w1, v1.z, acc.z); acc.w = fmaf(w1, v1.w, acc.w);
                acc.x = fmaf(w2, v2.x, acc.x); acc.y = fmaf(w2, v2.y, acc.y);
                acc.z = fmaf(w2, v2.z, acc.z); acc.w = fmaf(w2, v2.w, acc.w);
                acc.x = fmaf(w3, v3.x, acc.x); acc.y = fmaf(w3, v3.y, acc.y);
                acc.z = fmaf(w3, v3.z, acc.z); acc.w = fmaf(w3, v3.w, acc.w);
            }
        }
        // self-loop (already dinv-scaled)
        if (grp == 0) {
            float4 sv = X4[(unsigned)((node << 4) + sub)];
            acc.x += sv.x; acc.y += sv.y; acc.z += sv.z; acc.w += sv.w;
        }
        // reduce the 4 edge-groups; lane ends with agg[4*sub .. 4*sub+3]
        acc.x += __shfl_xor(acc.x, 16, 64); acc.y += __shfl_xor(acc.y, 16, 64);
        acc.z += __shfl_xor(acc.z, 16, 64); acc.w += __shfl_xor(acc.w, 16, 64);
        acc.x += __shfl_xor(acc.x, 32, 64); acc.y += __shfl_xor(acc.y, 32, 64);
        acc.z += __shfl_xor(acc.z, 32, 64); acc.w += __shfl_xor(acc.w, 32, 64);

        // matvec: out_j = sum_c sum_r agg[4c+r] * W[4c+r][j]
        float o = 0.f;
        #pragma unroll
        for (int c = 0; c < 16; ++c) {
            float4 wvv = *(const float4*)&sWt[lane * 64 + ((c ^ (lane & 15)) * 4)];
            float a0 = __int_as_float(__builtin_amdgcn_readlane(__float_as_int(acc.x), c));
            float a1 = __int_as_float(__builtin_amdgcn_readlane(__float_as_int(acc.y), c));
            float a2 = __int_as_float(__builtin_amdgcn_readlane(__float_as_int(acc.z), c));
            float a3 = __int_as_float(__builtin_amdgcn_readlane(__float_as_int(acc.w), c));
            o = fmaf(a0, wvv.x, o); o = fmaf(a1, wvv.y, o);
            o = fmaf(a2, wvv.z, o); o = fmaf(a3, wvv.w, o);
        }
        float di = dinv[node];
        float vv = o * di + bj;
        if (do_relu) vv = fmaxf(vv, 0.f);
        if (scale_out) vv *= di;
        out[(unsigned)(node * 64 + lane)] = vv;
    }
}

// ---- pooling / classifier ------------------------------------------------

__global__ void pool1_kernel(const float* __restrict__ H, const int* __restrict__ batch,
                             float* __restrict__ partial, int n) {
    int g = blockIdx.x >> 4, sl = blockIdx.x & (NSLICE - 1);
    int lo = 0, hi = n;
    while (lo < hi) { int m = (lo + hi) >> 1; if (batch[m] < g) lo = m + 1; else hi = m; }
    int start = lo;
    lo = start; hi = n;
    while (lo < hi) { int m = (lo + hi) >> 1; if (batch[m] < g + 1) lo = m + 1; else hi = m; }
    int end = lo;
    int len = end - start;
    int ss = start + (int)((long long)len * sl / NSLICE);
    int se = start + (int)((long long)len * (sl + 1) / NSLICE);

    int f = threadIdx.x & 63, c = threadIdx.x >> 6;
    float s = 0.f, m = -INFINITY;
    for (int i = ss + c; i < se; i += 4) {
        float v = H[i * NF + f];
        s += v; m = fmaxf(m, v);
    }
    __shared__ float ssh[4][64], smh[4][64];
    ssh[c][f] = s; smh[c][f] = m;
    __syncthreads();
    if (c == 0) {
        float sum = ssh[0][f] + ssh[1][f] + ssh[2][f] + ssh[3][f];
        float mx = fmaxf(fmaxf(smh[0][f], smh[1][f]), fmaxf(smh[2][f], smh[3][f]));
        partial[(size_t)blockIdx.x * 128 + f] = sum;
        partial[(size_t)blockIdx.x * 128 + 64 + f] = mx;
    }
}

__global__ void pool2_kernel(const float* __restrict__ partial, const int* __restrict__ batch,
                             const float* __restrict__ Wlin, const float* __restrict__ blin,
                             float* __restrict__ out, int n) {
    int g = blockIdx.x;
    int t = threadIdx.x;  // 128
    __shared__ float pooled[128];
    if (t < 64) {
        float sum = 0.f;
        for (int sl = 0; sl < NSLICE; ++sl) sum += partial[((size_t)g * NSLICE + sl) * 128 + t];
        int lo = 0, hi = n;
        while (lo < hi) { int m = (lo + hi) >> 1; if (batch[m] < g) lo = m + 1; else hi = m; }
        int start = lo;
        lo = start; hi = n;
        while (lo < hi) { int m = (lo + hi) >> 1; if (batch[m] < g + 1) lo = m + 1; else hi = m; }
        int cnt = lo - start;
        pooled[t] = sum / fmaxf((float)cnt, 1.0f);
    } else {
        int f = t - 64;
        float mx = -INFINITY;
        for (int sl = 0; sl < NSLICE; ++sl)
            mx = fmaxf(mx, partial[((size_t)g * NSLICE + sl) * 128 + 64 + f]);
        pooled[t] = mx;
    }
    __syncthreads();
    if (t < NC) {
        float acc = blin[t];
        #pragma unroll 8
        for (int k = 0; k < 128; ++k) acc = fmaf(pooled[k], Wlin[k * NC + t], acc);
        out[g * NC + t] = acc;
    }
}

// ---- launch ---------------------------------------------------------------

extern "C" void kernel_launch(void* const* d_in, const int* in_sizes, int n_in,
                              void* d_out, int out_size, void* d_ws, size_t ws_size,
                              hipStream_t stream) {
    const float* x     = (const float*)d_in[0];
    const int*   ei    = (const int*)d_in[1];
    const int*   batch = (const int*)d_in[2];
    const float* W1    = (const float*)d_in[3];
    const float* b1    = (const float*)d_in[4];
    const float* W2    = (const float*)d_in[5];
    const float* b2    = (const float*)d_in[6];
    const float* W3    = (const float*)d_in[7];
    const float* b3    = (const float*)d_in[8];
    const float* Wlin  = (const float*)d_in[9];
    const float* blin  = (const float*)d_in[10];
    const int* src = ei;
    const int* dst = ei + NE;
    float* out = (float*)d_out;

    // workspace layout (ints; all segments 16B aligned)
    int*   bcur    = (int*)d_ws;                     // 256
    int2*  rse     = (int2*)(bcur + 256);            // 50048 int2
    int*   csr_src = (int*)(rse + 50048);            // 196*4608 = 903168
    float* dinv    = (float*)(csr_src + NBKT * CAPB);// 50048
    float* bufA    = dinv + 50048;                   // 3.2M
    float* bufB    = bufA + (size_t)NN * NF;         // 3.2M (pairs alias, build only)
    int2*  pairs   = (int2*)bufB;                    // 196*4608*8B = 7.2MB <= 12.8MB
    float* partial = bufA;                           // alias: bufA free after layer 3

    // build: fixed-capacity bucket sort + dinv + prescale
    init_kernel<<<1, 256, 0, stream>>>(bcur);
    bscatter_kernel<<<(NE + CH - 1) / CH, 256, 0, stream>>>(src, dst, bcur, pairs, NE);
    bsort_kernel<<<NBKT, 256, 0, stream>>>(pairs, bcur, csr_src, rse, dinv, x, bufA, NN);

    // 3 fused GCN layers (32 nodes per block, 4 per wave, 8 waves)
    int lgrid = (NN + 31) / 32;  // 1563
    layer_kernel<<<lgrid, 512, 0, stream>>>(bufA, rse, csr_src, dinv, W1, b1,
                                            bufB, NN, 1, 1);
    layer_kernel<<<lgrid, 512, 0, stream>>>(bufB, rse, csr_src, dinv, W2, b2,
                                            bufA, NN, 1, 1);
    layer_kernel<<<lgrid, 512, 0, stream>>>(bufA, rse, csr_src, dinv, W3, b3,
                                            bufB, NN, 0, 0);

    // two-stage pool + fused classifier (partial aliases bufA)
    pool1_kernel<<<NG * NSLICE, 256, 0, stream>>>(bufB, batch, partial, NN);
    pool2_kernel<<<NG, 128, 0, stream>>>(partial, batch, Wlin, blin, out, NN);
}